// Round 11
// baseline (159.265 us; speedup 1.0000x reference)
//
#include <hip/hip_runtime.h>

#define NB 4096
#define DK 768
#define SCALE_S 0.5295756522f

typedef float f32x4 __attribute__((ext_vector_type(4)));
typedef __bf16 bf16x8 __attribute__((ext_vector_type(8)));

// ---- ws layout (bytes) ----
#define OFF_XB      0u            // 4096*768 bf16 = 6291456
#define OFF_YB      6291456u
#define OFF_ROWPM   12582912u     // 16*4096 f32 (region reserved 512KB)
#define OFF_ROWPS   13107200u
#define OFF_COLPM   13631488u
#define OFF_COLPS   14155776u
#define OFF_BITS    14712832u     // 4096 u32
#define OFF_CSPART  14729216u     // 16*32 int
#define OFF_DOTP    14731264u     // 256 f32
#define OFF_WSUM    14732288u     // 32 f32
#define OFF_PROBE   14736384u     // probe dump (dead scratch, ~12KB)

static __device__ __forceinline__ unsigned short f2bf(float f) {
  union { float f; unsigned u; } x; x.f = f;
  unsigned r = x.u + 0x7fffu + ((x.u >> 16) & 1u);   // RNE
  return (unsigned short)(r >> 16);
}

static __device__ __forceinline__ void gload16(const void* g, void* l) {
  __builtin_amdgcn_global_load_lds(
      (const __attribute__((address_space(1))) unsigned int*)g,
      (__attribute__((address_space(3))) unsigned int*)l,
      16, 0, 0);
}

// K1: fused prep. Blocks 0..15: pack label bits + colsum partials.
// Blocks 16..: fp32->bf16 conversion of X and Y (grid-stride).
__global__ void k_prep(const int* __restrict__ labels, unsigned* __restrict__ bits,
                       int* __restrict__ csPart,
                       const float* __restrict__ X, const float* __restrict__ Y,
                       unsigned short* __restrict__ Xb, unsigned short* __restrict__ Yb) {
  int t = threadIdx.x;
  if (blockIdx.x < 16) {
    __shared__ int cs[32];
    if (t < 32) cs[t] = 0;
    __syncthreads();
    int i = blockIdx.x * 256 + t;
    const int* row = labels + (size_t)i * 32;
    unsigned b = 0;
#pragma unroll
    for (int j = 0; j < 32; ++j) if (row[j] != 0) b |= (1u << j);
    bits[i] = b;
#pragma unroll
    for (int j = 0; j < 32; ++j) if (b & (1u << j)) atomicAdd(&cs[j], 1);
    __syncthreads();
    if (t < 32) csPart[blockIdx.x * 32 + t] = cs[t];
  } else {
    const int N4 = (NB * DK) / 4;  // 786432
    const int stride = (gridDim.x - 16) * 256;
    for (int idx = (blockIdx.x - 16) * 256 + t; idx < 2 * N4; idx += stride) {
      float4 v; unsigned short* dst;
      if (idx < N4) { v = ((const float4*)X)[idx]; dst = Xb + (size_t)idx * 4; }
      else          { v = ((const float4*)Y)[idx - N4]; dst = Yb + (size_t)(idx - N4) * 4; }
      uint2 p;
      p.x = (unsigned)f2bf(v.x) | ((unsigned)f2bf(v.y) << 16);
      p.y = (unsigned)f2bf(v.z) | ((unsigned)f2bf(v.w) << 16);
      *(uint2*)dst = p;
    }
  }
}

// ---- shared geometry macros (k_gemm + probes) ----
#define STAGEU(DBUF, ISB, H, KT) do { \
    char* _lb = lds + (DBUF) * 65536 + (ISB) * 32768 + (H) * 16384 + wave * 1024; \
    const unsigned short* _g = ((ISB) ? pB : pA) + (size_t)(H) * 128 * DK + (size_t)(KT) * 64; \
    gload16(_g, _lb); \
    gload16(_g + (size_t)64 * DK, _lb + 8192); \
  } while (0)

#define STAGE_T(DBUF, KT) do { \
    STAGEU(DBUF, 0, 0, KT); STAGEU(DBUF, 0, 1, KT); \
    STAGEU(DBUF, 1, 0, KT); STAGEU(DBUF, 1, 1, KT); \
  } while (0)

#define GEMM_SETUP_SWIZZLE() \
  const int bid = blockIdx.x; \
  const int xcd = bid & 7, loc = bid >> 3; \
  const int rb = (xcd & 3) * 4 + (loc >> 3); \
  const int cb = (xcd >> 2) * 8 + (loc & 7); \
  const int laneSw8 = ((lane & 7) ^ (lane >> 3)) * 8; \
  const unsigned short* pA = Xb + (size_t)(rb * 256 + wave * 8 + (lane >> 3)) * DK + laneSw8; \
  const unsigned short* pB = Yb + (size_t)(cb * 256 + wave * 8 + (lane >> 3)) * DK + laneSw8;

#define GEMM_FRAG_OFFSETS() \
  const int swz = (lane & 7) << 4; \
  const int offk0 = ((lane >> 4) * 16) ^ swz; \
  const int offk1 = (64 + (lane >> 4) * 16) ^ swz; \
  const int rowA0 = (wr * 128 + (lane & 15)) * 128; \
  const int rowB0 = (wc * 64 + (lane & 15)) * 128;

#define GEMM_TILE_COMPUTE(CURBUF) do { \
    const char* _c = lds + (CURBUF) * 65536; \
    bf16x8 bB[4][2]; \
    _Pragma("unroll") for (int n = 0; n < 4; ++n) { \
      bB[n][0] = *(const bf16x8*)(_c + 32768 + rowB0 + n * 2048 + offk0); \
      bB[n][1] = *(const bf16x8*)(_c + 32768 + rowB0 + n * 2048 + offk1); \
    } \
    __builtin_amdgcn_s_setprio(1); \
    _Pragma("unroll") for (int m2 = 0; m2 < 4; ++m2) { \
      bf16x8 a00 = *(const bf16x8*)(_c + rowA0 + (2 * m2) * 2048 + offk0); \
      bf16x8 a01 = *(const bf16x8*)(_c + rowA0 + (2 * m2) * 2048 + offk1); \
      bf16x8 a10 = *(const bf16x8*)(_c + rowA0 + (2 * m2 + 1) * 2048 + offk0); \
      bf16x8 a11 = *(const bf16x8*)(_c + rowA0 + (2 * m2 + 1) * 2048 + offk1); \
      _Pragma("unroll") for (int n = 0; n < 4; ++n) { \
        acc[2 * m2][n]     = __builtin_amdgcn_mfma_f32_16x16x32_bf16(a00, bB[n][0], acc[2 * m2][n], 0, 0, 0); \
        acc[2 * m2][n]     = __builtin_amdgcn_mfma_f32_16x16x32_bf16(a01, bB[n][1], acc[2 * m2][n], 0, 0, 0); \
        acc[2 * m2 + 1][n] = __builtin_amdgcn_mfma_f32_16x16x32_bf16(a10, bB[n][0], acc[2 * m2 + 1][n], 0, 0, 0); \
        acc[2 * m2 + 1][n] = __builtin_amdgcn_mfma_f32_16x16x32_bf16(a11, bB[n][1], acc[2 * m2 + 1][n], 0, 0, 0); \
      } \
    } \
    __builtin_amdgcn_s_setprio(0); \
  } while (0)

// K4: 256x256 bf16 MFMA GEMM (R10: BK=64, 2x64KB dbuf, depth-1 prefetch, one
// compiler-scheduled body + one __syncthreads per tile, verified XOR swizzle).
__launch_bounds__(512, 2)
__global__ void k_gemm(const unsigned short* __restrict__ Xb,
                       const unsigned short* __restrict__ Yb,
                       const unsigned* __restrict__ bits,
                       float* __restrict__ rowPM, float* __restrict__ rowPS,
                       float* __restrict__ colPM, float* __restrict__ colPS,
                       float* __restrict__ dotPart) {
  extern __shared__ char lds[];

  const int t = threadIdx.x;             // 0..511
  const int wave = t >> 6, lane = t & 63;
  const int wr = wave >> 2, wc = wave & 3;

  GEMM_SETUP_SWIZZLE();
  GEMM_FRAG_OFFSETS();

  f32x4 acc[8][4];
#pragma unroll
  for (int m = 0; m < 8; ++m)
#pragma unroll
    for (int n = 0; n < 4; ++n) acc[m][n] = (f32x4){0.f, 0.f, 0.f, 0.f};

  // prologue: stage tile0 into buf0, wait, barrier
  STAGE_T(0, 0);
  asm volatile("s_waitcnt vmcnt(0)" ::: "memory");
  __builtin_amdgcn_s_barrier();

#pragma unroll 1
  for (int kt = 0; kt < 12; ++kt) {
    const int cur = kt & 1;
    if (kt < 11) {
      if (cur) STAGE_T(0, kt + 1); else STAGE_T(1, kt + 1);
    }
    GEMM_TILE_COMPUTE(cur);
    __syncthreads();   // drains vmcnt(0)+lgkmcnt(0): tile kt+1 landed, buf safe
  }

  // ---- epilogue ----
  float* fb    = (float*)lds;
  float* redM  = fb;                       // 1024
  float* redS  = fb + 1024;                // 1024
  float* redM2 = fb + 2048;                // 512
  float* redS2 = fb + 2560;                // 512
  unsigned* bR = (unsigned*)(fb + 3072);   // 256
  unsigned* bC = bR + 256;                 // 256
  float* wred  = (float*)(bC + 256);       // 8

  if (t < 256) bR[t] = bits[rb * 256 + t];
  else         bC[t - 256] = bits[cb * 256 + (t - 256)];

  // (a) row partials. C/D layout: col = lane&15, row = (lane>>4)*4 + reg [m89/m91]
#pragma unroll
  for (int m = 0; m < 8; ++m) {
#pragma unroll
    for (int r = 0; r < 4; ++r) {
      float v0 = SCALE_S * acc[m][0][r];
      float v1 = SCALE_S * acc[m][1][r];
      float v2 = SCALE_S * acc[m][2][r];
      float v3 = SCALE_S * acc[m][3][r];
      float mx = fmaxf(fmaxf(v0, v1), fmaxf(v2, v3));
#pragma unroll
      for (int off = 1; off < 16; off <<= 1) mx = fmaxf(mx, __shfl_xor(mx, off));
      float sm = __expf(v0 - mx) + __expf(v1 - mx) + __expf(v2 - mx) + __expf(v3 - mx);
#pragma unroll
      for (int off = 1; off < 16; off <<= 1) sm += __shfl_xor(sm, off);
      if ((lane & 15) == 0) {
        int row = wr * 128 + m * 16 + (lane >> 4) * 4 + r;
        redM[row * 4 + wc] = mx; redS[row * 4 + wc] = sm;
      }
    }
  }
  // col partials
#pragma unroll
  for (int n = 0; n < 4; ++n) {
    float mx = -3.0e38f;
#pragma unroll
    for (int m = 0; m < 8; ++m)
#pragma unroll
      for (int r = 0; r < 4; ++r) mx = fmaxf(mx, SCALE_S * acc[m][n][r]);
    mx = fmaxf(mx, __shfl_xor(mx, 16));
    mx = fmaxf(mx, __shfl_xor(mx, 32));
    float sm = 0.f;
#pragma unroll
    for (int m = 0; m < 8; ++m)
#pragma unroll
      for (int r = 0; r < 4; ++r) sm += __expf(SCALE_S * acc[m][n][r] - mx);
    sm += __shfl_xor(sm, 16);
    sm += __shfl_xor(sm, 32);
    if (lane < 16) {
      int col = wc * 64 + n * 16 + lane;
      redM2[col * 2 + wr] = mx; redS2[col * 2 + wr] = sm;
    }
  }
  __syncthreads();

  // (b) W.C tile sum: popcount(bits_row & bits_col) * C (unscaled)
  float ws = 0.f;
  {
    unsigned bc[4];
#pragma unroll
    for (int n = 0; n < 4; ++n) bc[n] = bC[wc * 64 + n * 16 + (lane & 15)];
#pragma unroll
    for (int m = 0; m < 8; ++m) {
#pragma unroll
      for (int r = 0; r < 4; ++r) {
        unsigned br = bR[wr * 128 + m * 16 + (lane >> 4) * 4 + r];
#pragma unroll
        for (int n = 0; n < 4; ++n)
          ws += (float)__popc(br & bc[n]) * acc[m][n][r];
      }
    }
  }
#pragma unroll
  for (int off = 32; off; off >>= 1) ws += __shfl_xor(ws, off);
  if (lane == 0) wred[wave] = ws;

  // combine partials -> per-(block,row/col) (M,S)
  if (t < 256) {
    float M = fmaxf(fmaxf(redM[t * 4 + 0], redM[t * 4 + 1]),
                    fmaxf(redM[t * 4 + 2], redM[t * 4 + 3]));
    float S = 0.f;
#pragma unroll
    for (int k = 0; k < 4; ++k) S += redS[t * 4 + k] * __expf(redM[t * 4 + k] - M);
    rowPM[(size_t)cb * NB + rb * 256 + t] = M;
    rowPS[(size_t)cb * NB + rb * 256 + t] = S;
  } else {
    int c = t - 256;
    float m0 = redM2[c * 2 + 0], m1 = redM2[c * 2 + 1];
    float M = fmaxf(m0, m1);
    float S = redS2[c * 2 + 0] * __expf(m0 - M) + redS2[c * 2 + 1] * __expf(m1 - M);
    colPM[(size_t)rb * NB + cb * 256 + c] = M;
    colPS[(size_t)rb * NB + cb * 256 + c] = S;
  }
  __syncthreads();
  if (t == 0) {
    float s = 0.f;
#pragma unroll
    for (int w = 0; w < 8; ++w) s += wred[w];
    dotPart[bid] = s;
  }
}

// PROBE A: staging-only replica of k_gemm's main loop (48 iterations = 4x).
// Identical grid/LDS/addresses; no ds_read/MFMA. Measures the staging pipe alone.
__launch_bounds__(512, 2)
__global__ void k_probe_stage(const unsigned short* __restrict__ Xb,
                              const unsigned short* __restrict__ Yb,
                              float* __restrict__ dump) {
  extern __shared__ char lds[];
  const int t = threadIdx.x;
  const int wave = t >> 6, lane = t & 63;
  GEMM_SETUP_SWIZZLE();

  STAGE_T(0, 0);
  asm volatile("s_waitcnt vmcnt(0)" ::: "memory");
  __builtin_amdgcn_s_barrier();

#pragma unroll 1
  for (int kt = 0; kt < 48; ++kt) {
    if (kt < 47) STAGE_T((kt + 1) & 1, (kt + 1) % 12);
    __syncthreads();   // same per-tile drain as k_gemm
  }
  if (t == 0) dump[bid] = (float)(unsigned char)lds[0];
}

// PROBE B: ds_read+MFMA-only replica (48 iterations = 4x), LDS pre-initialized,
// no staging. Measures the LDS-read + MFMA pipes alone.
__launch_bounds__(512, 2)
__global__ void k_probe_mfma(float* __restrict__ dump) {
  extern __shared__ char lds[];
  const int t = threadIdx.x;
  const int wave = t >> 6, lane = t & 63;
  const int wr = wave >> 2, wc = wave & 3;
  GEMM_FRAG_OFFSETS();

  // init both 64KB buffers with bf16 1.0 pattern (deterministic)
  for (int i = t; i < 32768; i += 512) ((unsigned*)lds)[i] = 0x3f803f80u;
  __syncthreads();

  f32x4 acc[8][4];
#pragma unroll
  for (int m = 0; m < 8; ++m)
#pragma unroll
    for (int n = 0; n < 4; ++n) acc[m][n] = (f32x4){0.f, 0.f, 0.f, 0.f};

#pragma unroll 1
  for (int kt = 0; kt < 48; ++kt) {
    GEMM_TILE_COMPUTE(kt & 1);
    __syncthreads();
  }
  float s = 0.f;
#pragma unroll
  for (int m = 0; m < 8; ++m)
#pragma unroll
    for (int n = 0; n < 4; ++n)
#pragma unroll
      for (int r = 0; r < 4; ++r) s += acc[m][n][r];
#pragma unroll
  for (int off = 32; off; off >>= 1) s += __shfl_xor(s, off);
  if (lane == 0) dump[blockIdx.x * 8 + wave] = s;
}

// K5: combine 16 lse partials per row/col AND fold in the rw-weighted sum
__global__ void k_tail(const float* __restrict__ rowPM, const float* __restrict__ rowPS,
                       const float* __restrict__ colPM, const float* __restrict__ colPS,
                       const unsigned* __restrict__ bits, const int* __restrict__ csPart,
                       float* __restrict__ wsum) {
  __shared__ int cs[32];
  __shared__ float red[256];
  int t = threadIdx.x, b = blockIdx.x;
  if (t < 32) {
    int s = 0;
    for (int k = 0; k < 16; ++k) s += csPart[k * 32 + t];
    cs[t] = s;
  }
  __syncthreads();
  int g = b * 256 + t;   // 0..8191
  int i; float M = -3.0e38f, S = 0.f;
  if (g < NB) {
    i = g;
#pragma unroll
    for (int c = 0; c < 16; ++c) M = fmaxf(M, rowPM[(size_t)c * NB + i]);
#pragma unroll
    for (int c = 0; c < 16; ++c) S += rowPS[(size_t)c * NB + i] * __expf(rowPM[(size_t)c * NB + i] - M);
  } else {
    i = g - NB;
#pragma unroll
    for (int c = 0; c < 16; ++c) M = fmaxf(M, colPM[(size_t)c * NB + i]);
#pragma unroll
    for (int c = 0; c < 16; ++c) S += colPS[(size_t)c * NB + i] * __expf(colPM[(size_t)c * NB + i] - M);
  }
  float lse = M + __logf(S);
  unsigned bb = bits[i];
  int rw = 0;
#pragma unroll
  for (int j = 0; j < 32; ++j) if (bb & (1u << j)) rw += cs[j];
  red[t] = (float)rw * lse;
  __syncthreads();
  for (int s = 128; s; s >>= 1) {
    if (t < s) red[t] += red[t + s];
    __syncthreads();
  }
  if (t == 0) wsum[b] = red[0];
}

// K7: finalize scalar loss from 32 wsum + 256 dot partials
__global__ void k_final(const float* __restrict__ wsum, const float* __restrict__ dotPart,
                        float* __restrict__ out) {
  __shared__ double red[256];
  int t = threadIdx.x;
  double a = 0.0;
  if (t < 32) a += (double)wsum[t];
  a -= 2.0 * (double)SCALE_S * (double)dotPart[t];
  red[t] = a;
  __syncthreads();
  for (int s = 128; s; s >>= 1) {
    if (t < s) red[t] += red[t + s];
    __syncthreads();
  }
  if (t == 0) out[0] = (float)(red[0] / (2.0 * (double)NB * 32.0));
}

extern "C" void kernel_launch(void* const* d_in, const int* in_sizes, int n_in,
                              void* d_out, int out_size, void* d_ws, size_t ws_size,
                              hipStream_t stream) {
  const float* X = (const float*)d_in[0];
  const float* Y = (const float*)d_in[1];
  const int* labels = (const int*)d_in[2];
  char* ws = (char*)d_ws;

  unsigned short* Xb = (unsigned short*)(ws + OFF_XB);
  unsigned short* Yb = (unsigned short*)(ws + OFF_YB);
  float* rowPM = (float*)(ws + OFF_ROWPM);
  float* rowPS = (float*)(ws + OFF_ROWPS);
  float* colPM = (float*)(ws + OFF_COLPM);
  float* colPS = (float*)(ws + OFF_COLPS);
  unsigned* bits = (unsigned*)(ws + OFF_BITS);
  int* csPart = (int*)(ws + OFF_CSPART);
  float* dotPart = (float*)(ws + OFF_DOTP);
  float* wsum = (float*)(ws + OFF_WSUM);
  float* probeDump = (float*)(ws + OFF_PROBE);

  (void)hipFuncSetAttribute((const void*)k_gemm,
                            hipFuncAttributeMaxDynamicSharedMemorySize, 131072);
  (void)hipFuncSetAttribute((const void*)k_probe_stage,
                            hipFuncAttributeMaxDynamicSharedMemorySize, 131072);
  (void)hipFuncSetAttribute((const void*)k_probe_mfma,
                            hipFuncAttributeMaxDynamicSharedMemorySize, 131072);

  k_prep<<<528, 256, 0, stream>>>(labels, bits, csPart, X, Y, Xb, Yb);
  k_gemm<<<256, 512, 131072, stream>>>(Xb, Yb, bits, rowPM, rowPS, colPM, colPS, dotPart);
  k_tail<<<32, 256, 0, stream>>>(rowPM, rowPS, colPM, colPS, bits, csPart, wsum);
  k_final<<<1, 256, 0, stream>>>(wsum, dotPart, (float*)d_out);

  // ---- diagnostic probes (dead scratch output; 48 tiles = 4x k_gemm's loop) ----
  k_probe_stage<<<256, 512, 131072, stream>>>(Xb, Yb, probeDump);
  k_probe_mfma<<<256, 512, 131072, stream>>>(probeDump + 256);
}

// Round 12
// 47.344 us; speedup vs baseline: 3.3640x; 3.3640x over previous
//
#include <hip/hip_runtime.h>

#define NB 4096
#define DK 768
#define DKB 768          // bytes per row in fp8
#define SCALE_S 0.5295756522f

typedef float f32x4 __attribute__((ext_vector_type(4)));
typedef int i32x4 __attribute__((ext_vector_type(4)));
typedef int i32x8 __attribute__((ext_vector_type(8)));

// ---- ws layout (bytes) ----
#define OFF_XQ      0u            // 4096*768 fp8 = 3145728
#define OFF_YQ      3145728u
#define OFF_ROWPM   12582912u     // 16*4096 f32 (region reserved 512KB)
#define OFF_ROWPS   13107200u
#define OFF_COLPM   13631488u
#define OFF_COLPS   14155776u
#define OFF_BITS    14712832u     // 4096 u32
#define OFF_CSPART  14729216u     // 16*32 int
#define OFF_DOTP    14731264u     // 256 f32
#define OFF_WSUM    14732288u     // 32 f32

// f32 -> OCP e4m3fn, RNE, saturate to 448, subnormal-correct
static __device__ __forceinline__ unsigned char f2e4m3(float f) {
  union { float f; unsigned u; } x; x.f = f;
  unsigned s = (x.u >> 24) & 0x80u;
  x.u &= 0x7FFFFFFFu;
  float af = x.f;
  if (af >= 448.f) return (unsigned char)(s | 0x7Eu);
  int e = (int)(x.u >> 23) - 127;
  int eq = e < -6 ? -6 : e;
  float scale = __int_as_float((unsigned)((3 - eq) + 127) << 23);  // 2^(3-eq)
  int q = (int)rintf(af * scale);                                  // [0,16)
  if (q == 16) { q = 8; ++eq; }
  if (e < -6) return (unsigned char)(s | (unsigned)q);             // subnormal (q==8 -> 0x08 ok)
  return (unsigned char)(s | (((unsigned)(eq + 7)) << 3) | ((unsigned)(q - 8)));
}

static __device__ __forceinline__ void gload16(const void* g, void* l) {
  __builtin_amdgcn_global_load_lds(
      (const __attribute__((address_space(1))) unsigned int*)g,
      (__attribute__((address_space(3))) unsigned int*)l,
      16, 0, 0);
}

// K1: fused prep. Blocks 0..15: pack label bits + colsum partials.
// Blocks 16..: fp32 -> e4m3 conversion of X and Y (grid-stride).
__global__ void k_prep(const int* __restrict__ labels, unsigned* __restrict__ bits,
                       int* __restrict__ csPart,
                       const float* __restrict__ X, const float* __restrict__ Y,
                       unsigned char* __restrict__ Xq, unsigned char* __restrict__ Yq) {
  int t = threadIdx.x;
  if (blockIdx.x < 16) {
    __shared__ int cs[32];
    if (t < 32) cs[t] = 0;
    __syncthreads();
    int i = blockIdx.x * 256 + t;
    const int* row = labels + (size_t)i * 32;
    unsigned b = 0;
#pragma unroll
    for (int j = 0; j < 32; ++j) if (row[j] != 0) b |= (1u << j);
    bits[i] = b;
#pragma unroll
    for (int j = 0; j < 32; ++j) if (b & (1u << j)) atomicAdd(&cs[j], 1);
    __syncthreads();
    if (t < 32) csPart[blockIdx.x * 32 + t] = cs[t];
  } else {
    const int N4 = (NB * DK) / 4;  // 786432
    const int stride = (gridDim.x - 16) * 256;
    for (int idx = (blockIdx.x - 16) * 256 + t; idx < 2 * N4; idx += stride) {
      float4 v; unsigned* dst;
      if (idx < N4) { v = ((const float4*)X)[idx]; dst = (unsigned*)Xq + idx; }
      else          { v = ((const float4*)Y)[idx - N4]; dst = (unsigned*)Yq + (idx - N4); }
      unsigned p = (unsigned)f2e4m3(v.x) | ((unsigned)f2e4m3(v.y) << 8) |
                   ((unsigned)f2e4m3(v.z) << 16) | ((unsigned)f2e4m3(v.w) << 24);
      *dst = p;
    }
  }
}

// K4: 256x256 MX-fp8 MFMA GEMM. BK=128 fp8 (= 128B/row, 6 K-tiles), 2x64KB LDS
// double-buffer, depth-1 prefetch, one compiler-scheduled body + one
// __syncthreads per tile (R10 schedule, half the tiles). 16x16x128 f8f6f4
// scaled MFMA with unity e8m0 scales (127). Verified 16B-granule XOR-row&7
// swizzle on both sides. Fused row/col (max,sumexp) + popcount W.C epilogue.
// LDS buf b: A[256r][128B] at b*65536, B at +32768.

#define STAGEU8(DBUF, ISB, H, KT) do { \
    char* _lb = lds + (DBUF) * 65536 + (ISB) * 32768 + (H) * 16384 + wave * 2048; \
    const unsigned char* _g = ((ISB) ? pB : pA) + (size_t)(H) * 128 * DKB + (size_t)(KT) * 128; \
    gload16(_g, _lb); \
    gload16(_g + (size_t)8 * DKB, _lb + 1024); \
  } while (0)

#define STAGE_T8(DBUF, KT) do { \
    STAGEU8(DBUF, 0, 0, KT); STAGEU8(DBUF, 0, 1, KT); \
    STAGEU8(DBUF, 1, 0, KT); STAGEU8(DBUF, 1, 1, KT); \
  } while (0)

// load a 32B k-chunk fragment (two swizzled b128 reads) into v8i32
#define LOADFRAG(DST, BASE) do { \
    i32x4 _lo = *(const i32x4*)((BASE) + offg0); \
    i32x4 _hi = *(const i32x4*)((BASE) + offg1); \
    DST[0] = _lo[0]; DST[1] = _lo[1]; DST[2] = _lo[2]; DST[3] = _lo[3]; \
    DST[4] = _hi[0]; DST[5] = _hi[1]; DST[6] = _hi[2]; DST[7] = _hi[3]; \
  } while (0)

__launch_bounds__(512, 2)
__global__ void k_gemm(const unsigned char* __restrict__ Xq,
                       const unsigned char* __restrict__ Yq,
                       const unsigned* __restrict__ bits,
                       float* __restrict__ rowPM, float* __restrict__ rowPS,
                       float* __restrict__ colPM, float* __restrict__ colPS,
                       float* __restrict__ dotPart) {
  extern __shared__ char lds[];

  const int t = threadIdx.x;             // 0..511
  const int wave = t >> 6, lane = t & 63;
  const int wr = wave >> 2, wc = wave & 3;

  // bijective XCD-aware swizzle: each XCD gets a 4rb x 8cb sub-grid (16x16 grid)
  const int bid = blockIdx.x;
  const int xcd = bid & 7, loc = bid >> 3;
  const int rb = (xcd & 3) * 4 + (loc >> 3);
  const int cb = (xcd >> 2) * 8 + (loc & 7);

  // staging source (pre-swizzled 16B granule per lane; row_local&7 == lane>>3)
  const int g0 = ((lane & 7) ^ (lane >> 3)) * 16;
  const unsigned char* pA = Xq + (size_t)(rb * 256 + wave * 16 + (lane >> 3)) * DKB + g0;
  const unsigned char* pB = Yq + (size_t)(cb * 256 + wave * 16 + (lane >> 3)) * DKB + g0;

  // fragment read offsets (bytes); row&7 == lrow&7 for all m,n
  const int lrow = lane & 15;
  const int s7 = lrow & 7;
  const int gp = (lane >> 4) * 2;                    // granule pair base
  const int offg0 = ((gp) ^ s7) * 16;
  const int offg1 = ((gp + 1) ^ s7) * 16;
  const int rowA0 = (wr * 128 + lrow) * 128;         // + m*2048
  const int rowB0 = 32768 + (wc * 64 + lrow) * 128;  // + n*2048

  f32x4 acc[8][4];
#pragma unroll
  for (int m = 0; m < 8; ++m)
#pragma unroll
    for (int n = 0; n < 4; ++n) acc[m][n] = (f32x4){0.f, 0.f, 0.f, 0.f};

  // prologue: stage tile0 into buf0
  STAGE_T8(0, 0);
  asm volatile("s_waitcnt vmcnt(0)" ::: "memory");
  __builtin_amdgcn_s_barrier();

#pragma unroll 1
  for (int kt = 0; kt < 6; ++kt) {
    const int cur = kt & 1;
    if (kt < 5) {
      if (cur) STAGE_T8(0, kt + 1); else STAGE_T8(1, kt + 1);
    }
    const char* _c = lds + cur * 65536;
    i32x8 bF[4];
#pragma unroll
    for (int n = 0; n < 4; ++n) LOADFRAG(bF[n], _c + rowB0 + n * 2048);
    __builtin_amdgcn_s_setprio(1);
#pragma unroll
    for (int m = 0; m < 8; ++m) {
      i32x8 aF;
      LOADFRAG(aF, _c + rowA0 + m * 2048);
#pragma unroll
      for (int n = 0; n < 4; ++n)
        acc[m][n] = __builtin_amdgcn_mfma_scale_f32_16x16x128_f8f6f4(
            aF, bF[n], acc[m][n], 0, 0, 0, 127, 0, 127);
    }
    __builtin_amdgcn_s_setprio(0);
    __syncthreads();   // drains vmcnt(0)+lgkmcnt(0): tile kt+1 landed, buf safe
  }

  // ---- epilogue (C/D layout dtype-independent: col=lane&15, row=(lane>>4)*4+r) ----
  float* fb    = (float*)lds;
  float* redM  = fb;                       // 1024
  float* redS  = fb + 1024;                // 1024
  float* redM2 = fb + 2048;                // 512
  float* redS2 = fb + 2560;                // 512
  unsigned* bR = (unsigned*)(fb + 3072);   // 256
  unsigned* bC = bR + 256;                 // 256
  float* wred  = (float*)(bC + 256);       // 8

  if (t < 256) bR[t] = bits[rb * 256 + t];
  else         bC[t - 256] = bits[cb * 256 + (t - 256)];

  // (a) row partials
#pragma unroll
  for (int m = 0; m < 8; ++m) {
#pragma unroll
    for (int r = 0; r < 4; ++r) {
      float v0 = SCALE_S * acc[m][0][r];
      float v1 = SCALE_S * acc[m][1][r];
      float v2 = SCALE_S * acc[m][2][r];
      float v3 = SCALE_S * acc[m][3][r];
      float mx = fmaxf(fmaxf(v0, v1), fmaxf(v2, v3));
#pragma unroll
      for (int off = 1; off < 16; off <<= 1) mx = fmaxf(mx, __shfl_xor(mx, off));
      float sm = __expf(v0 - mx) + __expf(v1 - mx) + __expf(v2 - mx) + __expf(v3 - mx);
#pragma unroll
      for (int off = 1; off < 16; off <<= 1) sm += __shfl_xor(sm, off);
      if ((lane & 15) == 0) {
        int row = wr * 128 + m * 16 + (lane >> 4) * 4 + r;
        redM[row * 4 + wc] = mx; redS[row * 4 + wc] = sm;
      }
    }
  }
  // col partials
#pragma unroll
  for (int n = 0; n < 4; ++n) {
    float mx = -3.0e38f;
#pragma unroll
    for (int m = 0; m < 8; ++m)
#pragma unroll
      for (int r = 0; r < 4; ++r) mx = fmaxf(mx, SCALE_S * acc[m][n][r]);
    mx = fmaxf(mx, __shfl_xor(mx, 16));
    mx = fmaxf(mx, __shfl_xor(mx, 32));
    float sm = 0.f;
#pragma unroll
    for (int m = 0; m < 8; ++m)
#pragma unroll
      for (int r = 0; r < 4; ++r) sm += __expf(SCALE_S * acc[m][n][r] - mx);
    sm += __shfl_xor(sm, 16);
    sm += __shfl_xor(sm, 32);
    if (lane < 16) {
      int col = wc * 64 + n * 16 + lane;
      redM2[col * 2 + wr] = mx; redS2[col * 2 + wr] = sm;
    }
  }
  __syncthreads();

  // (b) W.C tile sum: popcount(bits_row & bits_col) * C (unscaled)
  float ws = 0.f;
  {
    unsigned bc[4];
#pragma unroll
    for (int n = 0; n < 4; ++n) bc[n] = bC[wc * 64 + n * 16 + (lane & 15)];
#pragma unroll
    for (int m = 0; m < 8; ++m) {
#pragma unroll
      for (int r = 0; r < 4; ++r) {
        unsigned br = bR[wr * 128 + m * 16 + (lane >> 4) * 4 + r];
#pragma unroll
        for (int n = 0; n < 4; ++n)
          ws += (float)__popc(br & bc[n]) * acc[m][n][r];
      }
    }
  }
#pragma unroll
  for (int off = 32; off; off >>= 1) ws += __shfl_xor(ws, off);
  if (lane == 0) wred[wave] = ws;

  // combine partials -> per-(block,row/col) (M,S)
  if (t < 256) {
    float M = fmaxf(fmaxf(redM[t * 4 + 0], redM[t * 4 + 1]),
                    fmaxf(redM[t * 4 + 2], redM[t * 4 + 3]));
    float S = 0.f;
#pragma unroll
    for (int k = 0; k < 4; ++k) S += redS[t * 4 + k] * __expf(redM[t * 4 + k] - M);
    rowPM[(size_t)cb * NB + rb * 256 + t] = M;
    rowPS[(size_t)cb * NB + rb * 256 + t] = S;
  } else {
    int c = t - 256;
    float m0 = redM2[c * 2 + 0], m1 = redM2[c * 2 + 1];
    float M = fmaxf(m0, m1);
    float S = redS2[c * 2 + 0] * __expf(m0 - M) + redS2[c * 2 + 1] * __expf(m1 - M);
    colPM[(size_t)rb * NB + cb * 256 + c] = M;
    colPS[(size_t)rb * NB + cb * 256 + c] = S;
  }
  __syncthreads();
  if (t == 0) {
    float s = 0.f;
#pragma unroll
    for (int w = 0; w < 8; ++w) s += wred[w];
    dotPart[bid] = s;
  }
}

// K5: combine 16 lse partials per row/col AND fold in the rw-weighted sum
__global__ void k_tail(const float* __restrict__ rowPM, const float* __restrict__ rowPS,
                       const float* __restrict__ colPM, const float* __restrict__ colPS,
                       const unsigned* __restrict__ bits, const int* __restrict__ csPart,
                       float* __restrict__ wsum) {
  __shared__ int cs[32];
  __shared__ float red[256];
  int t = threadIdx.x, b = blockIdx.x;
  if (t < 32) {
    int s = 0;
    for (int k = 0; k < 16; ++k) s += csPart[k * 32 + t];
    cs[t] = s;
  }
  __syncthreads();
  int g = b * 256 + t;   // 0..8191
  int i; float M = -3.0e38f, S = 0.f;
  if (g < NB) {
    i = g;
#pragma unroll
    for (int c = 0; c < 16; ++c) M = fmaxf(M, rowPM[(size_t)c * NB + i]);
#pragma unroll
    for (int c = 0; c < 16; ++c) S += rowPS[(size_t)c * NB + i] * __expf(rowPM[(size_t)c * NB + i] - M);
  } else {
    i = g - NB;
#pragma unroll
    for (int c = 0; c < 16; ++c) M = fmaxf(M, colPM[(size_t)c * NB + i]);
#pragma unroll
    for (int c = 0; c < 16; ++c) S += colPS[(size_t)c * NB + i] * __expf(colPM[(size_t)c * NB + i] - M);
  }
  float lse = M + __logf(S);
  unsigned bb = bits[i];
  int rw = 0;
#pragma unroll
  for (int j = 0; j < 32; ++j) if (bb & (1u << j)) rw += cs[j];
  red[t] = (float)rw * lse;
  __syncthreads();
  for (int s = 128; s; s >>= 1) {
    if (t < s) red[t] += red[t + s];
    __syncthreads();
  }
  if (t == 0) wsum[b] = red[0];
}

// K7: finalize scalar loss from 32 wsum + 256 dot partials
__global__ void k_final(const float* __restrict__ wsum, const float* __restrict__ dotPart,
                        float* __restrict__ out) {
  __shared__ double red[256];
  int t = threadIdx.x;
  double a = 0.0;
  if (t < 32) a += (double)wsum[t];
  a -= 2.0 * (double)SCALE_S * (double)dotPart[t];
  red[t] = a;
  __syncthreads();
  for (int s = 128; s; s >>= 1) {
    if (t < s) red[t] += red[t + s];
    __syncthreads();
  }
  if (t == 0) out[0] = (float)(red[0] / (2.0 * (double)NB * 32.0));
}

extern "C" void kernel_launch(void* const* d_in, const int* in_sizes, int n_in,
                              void* d_out, int out_size, void* d_ws, size_t ws_size,
                              hipStream_t stream) {
  const float* X = (const float*)d_in[0];
  const float* Y = (const float*)d_in[1];
  const int* labels = (const int*)d_in[2];
  char* ws = (char*)d_ws;

  unsigned char* Xq = (unsigned char*)(ws + OFF_XQ);
  unsigned char* Yq = (unsigned char*)(ws + OFF_YQ);
  float* rowPM = (float*)(ws + OFF_ROWPM);
  float* rowPS = (float*)(ws + OFF_ROWPS);
  float* colPM = (float*)(ws + OFF_COLPM);
  float* colPS = (float*)(ws + OFF_COLPS);
  unsigned* bits = (unsigned*)(ws + OFF_BITS);
  int* csPart = (int*)(ws + OFF_CSPART);
  float* dotPart = (float*)(ws + OFF_DOTP);
  float* wsum = (float*)(ws + OFF_WSUM);

  (void)hipFuncSetAttribute((const void*)k_gemm,
                            hipFuncAttributeMaxDynamicSharedMemorySize, 131072);

  k_prep<<<528, 256, 0, stream>>>(labels, bits, csPart, X, Y, Xq, Yq);
  k_gemm<<<256, 512, 131072, stream>>>(Xq, Yq, bits, rowPM, rowPS, colPM, colPS, dotPart);
  k_tail<<<32, 256, 0, stream>>>(rowPM, rowPS, colPM, colPS, bits, csPart, wsum);
  k_final<<<1, 256, 0, stream>>>(wsum, dotPart, (float*)d_out);
}